// Round 3
// baseline (672.220 us; speedup 1.0000x reference)
//
#include <hip/hip_runtime.h>

// Problem constants (fixed by reference)
#define N_B   8
#define C_CH  512
#define CT_T  256
#define L_T   64
#define HEADS 8
#define D_H   64
#define HW_PX 16384   // 128*128

typedef short    bf16x8 __attribute__((ext_vector_type(8)));
typedef float    f32x16 __attribute__((ext_vector_type(16)));
typedef unsigned u32x4  __attribute__((ext_vector_type(4)));

__device__ __forceinline__ unsigned pk_bf16(float lo, float hi) {
    unsigned r;
    asm("v_cvt_pk_bf16_f32 %0, %1, %2" : "=v"(r) : "v"(lo), "v"(hi));
    return r;
}
__device__ __forceinline__ float lo_f(unsigned w) { return __uint_as_float(w << 16); }
__device__ __forceinline__ float hi_f(unsigned w) { return __uint_as_float(w & 0xFFFF0000u); }

// Split 8 k-contiguous f32 into hi/lo bf16 packed fragments (bf16x3 trick):
// x = hi + lo with |err| ~ 2^-17 relative.
__device__ __forceinline__ void split8(const float x[8], u32x4& h, u32x4& l) {
#pragma unroll
    for (int j = 0; j < 4; ++j) {
        float a = x[2 * j], b = x[2 * j + 1];
        unsigned ph = pk_bf16(a, b);
        h[j] = ph;
        l[j] = pk_bf16(a - lo_f(ph), b - hi_f(ph));
    }
}

__device__ __forceinline__ f32x16 mfma_bf16(u32x4 a, u32x4 b, f32x16 c) {
    return __builtin_amdgcn_mfma_f32_32x32x16_bf16(
        __builtin_bit_cast(bf16x8, a), __builtin_bit_cast(bf16x8, b), c, 0, 0, 0);
}

// ---------------------------------------------------------------------------
// Kernel A (unchanged): v = Wv@token + bv, k = (Wk@token + bk) * (log2e/8).
// ---------------------------------------------------------------------------
__global__ __launch_bounds__(256) void proj_kernel(
    const float* __restrict__ token,
    const float* __restrict__ Wv, const float* __restrict__ bv,
    const float* __restrict__ Wk, const float* __restrict__ bk,
    float* __restrict__ vw, float* __restrict__ kw)
{
    int t = blockIdx.x * 256 + threadIdx.x;      // 8*512*64 = 262144 threads
    int l = t & (L_T - 1);
    int c = (t >> 6) & (C_CH - 1);
    int n = t >> 15;

    const float* tok = token + (size_t)n * CT_T * L_T + l;
    const float* wv  = Wv + (size_t)c * CT_T;
    const float* wk  = Wk + (size_t)c * CT_T;

    float av = 0.f, ak = 0.f;
#pragma unroll 8
    for (int ct = 0; ct < CT_T; ++ct) {
        float tv = tok[ct * L_T];
        av = fmaf(wv[ct], tv, av);
        ak = fmaf(wk[ct], tv, ak);
    }
    av += bv[c];
    ak += bk[c];
    const float kscale = 0.125f * 1.44269504088896340736f; // (1/sqrt(64)) * log2(e)
    vw[t] = av;
    kw[t] = ak * kscale;
}

// ---------------------------------------------------------------------------
// Kernel B: MFMA flash-attention, occupancy-tuned.
//
// Block = 256 threads (4 waves), one (n,h), 512 consecutive px.
// K/V live in LDS as PRE-SPLIT packed bf16 hi/lo MFMA A-fragments (32 KB);
// per-tile reads via ds_read_b128 (stride-16B, conflict-free).
//
// vs round 2: residual comes from an EPILOGUE re-read of feature (L1/L2 hit —
// same wave loaded those addresses ~1k cycles earlier) instead of 32 VGPRs of
// register-resident swapped Q. Peak VGPR drops ~150 -> ~120, so
// __launch_bounds__(256,4) gives 16 waves/CU (2x round 2's latency hiding).
//
// MFMA layouts (32x32x16_bf16):
//   A: row=lane&31, k=8*(lane>>5)+i   B: col=lane&31, k=8*(lane>>5)+i
//   C/D: col=lane&31, row=(r&3)+8*(r>>2)+4*(lane>>5)
// ---------------------------------------------------------------------------
__global__ __launch_bounds__(256, 4) void attn_kernel(
    const float* __restrict__ feature,
    const float* __restrict__ vw, const float* __restrict__ kw,
    float* __restrict__ out)
{
    __shared__ u32x4 ldsK[2][2][4][64];   // [hi/lo][t][s][lane]  16 KB
    __shared__ u32x4 ldsV[2][2][4][64];   // [hi/lo][u][s][lane]  16 KB

    const int tid  = threadIdx.x;
    const int lane = tid & 63;
    const int w    = tid >> 6;       // wave 0..3
    const int c    = lane & 31;
    const int hi   = lane >> 5;

    const int bid = blockIdx.x;      // 2048 = 32 px-groups * 64 (n,h)
    const int nh  = bid & 63;        // nh%8 -> fixed XCD: kw/vw L2-local
    const int grp = bid >> 6;        // 512-px group

    const float* Kb = kw + (size_t)nh * (D_H * L_T);   // K[dd][l]
    const float* Vb = vw + (size_t)nh * (D_H * L_T);   // V[dd][l]

    // ---- cooperative staging: waves 0,1 build K-frags (t=w), waves 2,3 V (u=w-2)
    if (w < 2) {
        const int t = w;
#pragma unroll
        for (int s = 0; s < 4; ++s) {
            float tmp[8];
#pragma unroll
            for (int i = 0; i < 8; ++i)
                tmp[i] = Kb[(16 * s + 8 * hi + i) * L_T + 32 * t + c];  // A[l][d] = K[d][l]
            u32x4 h, l;
            split8(tmp, h, l);
            ldsK[0][t][s][lane] = h;
            ldsK[1][t][s][lane] = l;
        }
    } else {
        const int u = w - 2;
#pragma unroll
        for (int s = 0; s < 4; ++s) {
            const float* p = Vb + (size_t)(32 * u + c) * L_T + 16 * s + 8 * hi; // 32B-aligned
            float4 q0 = *(const float4*)(p);
            float4 q1 = *(const float4*)(p + 4);
            float tmp[8] = {q0.x, q0.y, q0.z, q0.w, q1.x, q1.y, q1.z, q1.w};
            u32x4 h, l;
            split8(tmp, h, l);
            ldsV[0][u][s][lane] = h;
            ldsV[1][u][s][lane] = l;
        }
    }
    __syncthreads();

    const size_t fb = (size_t)nh * D_H * HW_PX;

#pragma unroll 1
    for (int it = 0; it < 4; ++it) {
        const int px = grp * 512 + w * 128 + it * 32 + c;

        // ---- QK^T: S^T[l][px]
        f32x16 accS[2];
#pragma unroll
        for (int r = 0; r < 16; ++r) { accS[0][r] = 0.f; accS[1][r] = 0.f; }

#pragma unroll
        for (int s = 0; s < 4; ++s) {
            float q[8];
#pragma unroll
            for (int i = 0; i < 8; ++i)        // Q[d][px]: 128B-coalesced per half-wave
                q[i] = feature[fb + (size_t)(16 * s + 8 * hi + i) * HW_PX + px];
            u32x4 qh, ql;
            split8(q, qh, ql);
            u32x4 kh0 = ldsK[0][0][s][lane];
            u32x4 kh1 = ldsK[0][1][s][lane];
            u32x4 kl0 = ldsK[1][0][s][lane];
            u32x4 kl1 = ldsK[1][1][s][lane];
            accS[0] = mfma_bf16(kh0, qh, accS[0]);
            accS[0] = mfma_bf16(kh0, ql, accS[0]);
            accS[0] = mfma_bf16(kl0, qh, accS[0]);
            accS[1] = mfma_bf16(kh1, qh, accS[1]);
            accS[1] = mfma_bf16(kh1, ql, accS[1]);
            accS[1] = mfma_bf16(kl1, qh, accS[1]);
        }

        // ---- softmax over l (base-2 domain; scale folded into kw)
        float m = accS[0][0];
#pragma unroll
        for (int r = 1; r < 16; ++r) m = fmaxf(m, accS[0][r]);
#pragma unroll
        for (int r = 0; r < 16; ++r) m = fmaxf(m, accS[1][r]);
        m = fmaxf(m, __shfl_xor(m, 32));
        float sum = 0.f;
#pragma unroll
        for (int t = 0; t < 2; ++t)
#pragma unroll
            for (int r = 0; r < 16; ++r) {
                float e = __builtin_amdgcn_exp2f(accS[t][r] - m);
                accS[t][r] = e;                 // unnormalized P in-place
                sum += e;
            }
        sum += __shfl_xor(sum, 32);
        const float rinv = 1.0f / sum;

        // ---- PV: O^T[dd][px]
        f32x16 accO[2];
#pragma unroll
        for (int r = 0; r < 16; ++r) { accO[0][r] = 0.f; accO[1][r] = 0.f; }

#pragma unroll
        for (int s = 0; s < 4; ++s) {
            const int t  = s >> 1;
            const int b0 = 8 * (s & 1);
            float e0 = accS[t][b0 + 0], e1 = accS[t][b0 + 1];
            float e2 = accS[t][b0 + 2], e3 = accS[t][b0 + 3];
            float e4 = accS[t][b0 + 4], e5 = accS[t][b0 + 5];
            float e6 = accS[t][b0 + 6], e7 = accS[t][b0 + 7];
            unsigned xh0 = pk_bf16(e0, e1), xh1 = pk_bf16(e2, e3);
            unsigned yh0 = pk_bf16(e4, e5), yh1 = pk_bf16(e6, e7);
            unsigned xl0 = pk_bf16(e0 - lo_f(xh0), e1 - hi_f(xh0));
            unsigned xl1 = pk_bf16(e2 - lo_f(xh1), e3 - hi_f(xh1));
            unsigned yl0 = pk_bf16(e4 - lo_f(yh0), e5 - hi_f(yh0));
            unsigned yl1 = pk_bf16(e6 - lo_f(yh1), e7 - hi_f(yh1));
            auto r0 = __builtin_amdgcn_permlane32_swap(xh0, yh0, false, false);
            auto r1 = __builtin_amdgcn_permlane32_swap(xh1, yh1, false, false);
            auto r2 = __builtin_amdgcn_permlane32_swap(xl0, yl0, false, false);
            auto r3 = __builtin_amdgcn_permlane32_swap(xl1, yl1, false, false);
            u32x4 pbh, pbl;
            pbh[0] = r0[0]; pbh[1] = r1[0]; pbh[2] = r0[1]; pbh[3] = r1[1];
            pbl[0] = r2[0]; pbl[1] = r3[0]; pbl[2] = r2[1]; pbl[3] = r3[1];
            u32x4 vh0 = ldsV[0][0][s][lane];
            u32x4 vh1 = ldsV[0][1][s][lane];
            u32x4 vl0 = ldsV[1][0][s][lane];
            u32x4 vl1 = ldsV[1][1][s][lane];
            accO[0] = mfma_bf16(vh0, pbh, accO[0]);
            accO[0] = mfma_bf16(vh0, pbl, accO[0]);
            accO[0] = mfma_bf16(vl0, pbh, accO[0]);
            accO[1] = mfma_bf16(vh1, pbh, accO[1]);
            accO[1] = mfma_bf16(vh1, pbl, accO[1]);
            accO[1] = mfma_bf16(vl1, pbh, accO[1]);
        }

        // ---- epilogue: normalize + residual (L1/L2-hit re-read) + store
#pragma unroll
        for (int u = 0; u < 2; ++u)
#pragma unroll
            for (int r = 0; r < 16; ++r) {
                const int dd = 32 * u + (r & 3) + 8 * (r >> 2) + 4 * hi;
                const size_t a = fb + (size_t)dd * HW_PX + px;
                out[a] = fmaf(accO[u][r], rinv, feature[a]);
            }
    }
}

// ---------------------------------------------------------------------------
extern "C" void kernel_launch(void* const* d_in, const int* in_sizes, int n_in,
                              void* d_out, int out_size, void* d_ws, size_t ws_size,
                              hipStream_t stream)
{
    const float* feature = (const float*)d_in[0];
    const float* token   = (const float*)d_in[1];
    const float* Wv      = (const float*)d_in[2];
    const float* bv      = (const float*)d_in[3];
    const float* Wk      = (const float*)d_in[4];
    const float* bk      = (const float*)d_in[5];
    float* out = (float*)d_out;

    float* vw = (float*)d_ws;                       // 262144 floats
    float* kw = vw + (size_t)N_B * C_CH * L_T;      // 262144 floats

    proj_kernel<<<(N_B * C_CH * L_T) / 256, 256, 0, stream>>>(token, Wv, bv, Wk, bk, vw, kw);

    // 32 px-groups (512 px each) x 64 (n,h), 4 waves per block
    attn_kernel<<<32 * 64, 256, 0, stream>>>(feature, vw, kw, out);
}